// Round 4
// baseline (2000.330 us; speedup 1.0000x reference)
//
#include <hip/hip_runtime.h>

#define NBATCH 256
#define SLEN   2048
#define NTAG   64
#define BOS_T  1
#define EOS_T  2

// bt: (S-1) rows x 64 bytes = 131008 -> 131072
#define BT_BYTES 131072
#define LDS_BYTES (BT_BYTES + NTAG * 4)

typedef float f32x4 __attribute__((ext_vector_type(4)));

// single-wave block: LDS visibility needs only lgkmcnt drain, NOT s_barrier
// (avoids the vmcnt(0) drain a real barrier implies -> prefetch stays in flight)
#define WAVE_FENCE() asm volatile("s_waitcnt lgkmcnt(0)" ::: "memory")

__global__ __launch_bounds__(64, 1)
void crf_viterbi(const float* __restrict__ emissions,  // [B,S,C]
                 const float* __restrict__ mask,       // [B,S]
                 const float* __restrict__ trans,      // [C,C]
                 int* __restrict__ out)                // [B,S] int32 tags
{
    extern __shared__ unsigned char lds[];
    unsigned char* bt = lds;                       // [S-1][64] backpointers
    float* alpha = (float*)(lds + BT_BYTES);       // [64], in-place update

    const int b = blockIdx.x;
    const int c = threadIdx.x;                     // current tag, 0..63

    // T column c: tc4[q][k] = T[4q+k][c], pinned in VGPRs via asm keep-alive
    f32x4 tc4[16];
    #pragma unroll
    for (int q = 0; q < 16; ++q) {
        tc4[q][0] = trans[(q * 4 + 0) * NTAG + c];
        tc4[q][1] = trans[(q * 4 + 1) * NTAG + c];
        tc4[q][2] = trans[(q * 4 + 2) * NTAG + c];
        tc4[q][3] = trans[(q * 4 + 3) * NTAG + c];
    }
    #pragma unroll
    for (int q = 0; q < 16; ++q) asm volatile("" : "+v"(tc4[q]));

    // length = sum(mask[b,:]) ; mask is left-contiguous 1s
    const float* mrow = mask + (size_t)b * SLEN;
    float msum = 0.f;
    #pragma unroll
    for (int k = 0; k < SLEN / 64; ++k) msum += mrow[c + k * 64];
    #pragma unroll
    for (int off = 32; off >= 1; off >>= 1) msum += __shfl_xor(msum, off, 64);
    const int len = (int)msum;                     // in [1024, 2048]

    const float* E = emissions + (size_t)b * SLEN * NTAG;

    // alpha0 = emissions[:,0] + T[BOS,:]
    alpha[c] = E[c] + tc4[BOS_T / 4][BOS_T % 4];
    WAVE_FENCE();

    // depth-2 emissions prefetch (2 outstanding loads, never drained by barrier)
    float e0 = E[1 * NTAG + c];                    // emit for t=1
    float e1 = E[((2 < len) ? 2 : (len - 1)) * NTAG + c];

    for (int t = 1; t < len; ++t) {
        float emit = e0;
        e0 = e1;
        int tn = (t + 2 < len) ? (t + 2) : (len - 1);
        e1 = E[tn * NTAG + c];                     // issued early, used in 2 iters

        const f32x4* a4 = (const f32x4*)alpha;

        // 4 independent chains over contiguous prev ranges [16j, 16j+16)
        float bestv[4];
        int   besti[4];
        #pragma unroll
        for (int j = 0; j < 4; ++j) {
            float bv = -3.402823466e38f;
            int   bi = 0;
            #pragma unroll
            for (int q = 0; q < 4; ++q) {
                f32x4 av = a4[j * 4 + q];
                const int p = j * 16 + q * 4;
                f32x4 tv = tc4[j * 4 + q];
                float cand;
                cand = av[0] + tv[0]; if (cand > bv) { bv = cand; bi = p + 0; }
                cand = av[1] + tv[1]; if (cand > bv) { bv = cand; bi = p + 1; }
                cand = av[2] + tv[2]; if (cand > bv) { bv = cand; bi = p + 2; }
                cand = av[3] + tv[3]; if (cand > bv) { bv = cand; bi = p + 3; }
            }
            bestv[j] = bv; besti[j] = bi;
        }
        // merge in ascending-prev order, strict > keeps first argmax
        float bv = bestv[0]; int bi = besti[0];
        if (bestv[1] > bv) { bv = bestv[1]; bi = besti[1]; }
        if (bestv[2] > bv) { bv = bestv[2]; bi = besti[2]; }
        if (bestv[3] > bv) { bv = bestv[3]; bi = besti[3]; }

        bt[(t - 1) * NTAG + c] = (unsigned char)bi;
        // in-place alpha update is safe: the write depends on all 64 reads,
        // and same-wave LDS ops execute in order; fence makes it visible.
        alpha[c] = bv + emit;
        WAVE_FENCE();
    }

    // final scores: alpha + T[:,EOS]
    float fin = alpha[c] + trans[c * NTAG + EOS_T];

    // wave argmax: value desc, index asc (first occurrence)
    float v = fin; int idx = c;
    #pragma unroll
    for (int off = 1; off < 64; off <<= 1) {
        float ov = __shfl_xor(v, off, 64);
        int   oi = __shfl_xor(idx, off, 64);
        if (ov > v || (ov == v && oi < idx)) { v = ov; idx = oi; }
    }
    int cur = idx;                                  // best_last (wave-uniform)

    int* orow = out + (size_t)b * SLEN;
    for (int t = len + c; t < SLEN; t += 64) orow[t] = 0;   // PAD tail
    if (c == 0) orow[len - 1] = cur;

    WAVE_FENCE();
    // backtrace through LDS backpointers (uniform addr -> broadcast read)
    for (int t = len - 2; t >= 0; --t) {
        cur = bt[t * NTAG + cur];
        if (c == 0) orow[t] = cur;
    }
}

extern "C" void kernel_launch(void* const* d_in, const int* in_sizes, int n_in,
                              void* d_out, int out_size, void* d_ws, size_t ws_size,
                              hipStream_t stream) {
    const float* emissions = (const float*)d_in[0];
    const float* mask      = (const float*)d_in[1];
    const float* trans     = (const float*)d_in[2];
    int* out = (int*)d_out;

    (void)hipFuncSetAttribute((const void*)crf_viterbi,
                              hipFuncAttributeMaxDynamicSharedMemorySize,
                              LDS_BYTES);

    crf_viterbi<<<NBATCH, 64, LDS_BYTES, stream>>>(emissions, mask, trans, out);
}